// Round 10
// baseline (146.096 us; speedup 1.0000x reference)
//
#include <hip/hip_runtime.h>
#include <stdint.h>

// Problem: LTCCell  B=256, I=512, H=512. ALL tensors float32, output float32.
// R9 counters: harness re-poisons the 256MiB ws at ~49us/replay -> fixed
// ~78us overhead in every total; only ~50us is kernel time. Accum's stubborn
// ~17us idle survived TLP/prefetch/trans/atomic removal -> last model:
// param RE-READ bandwidth (lane<->h mapping re-reads 8.4MB x 32 btiles =
// 268MB/dispatch from L2/L3 ~ 18us).
// R10: TRANSPOSE MAPPING: lane<->batch (256 thr = 256 b), register-block 16 h
// per thread. Params become wave-uniform (scalar-load path, K$ broadcast),
// each (row,h) param read by exactly ONE block: 268MB -> ~8.4MB unique.
// x/state via LDS [row][b] (padded, conflict-free). Partials h-major
// part[s][h][b] so stores AND reduce loads stay coalesced.
constexpr int NB    = 256;
constexpr int NH    = 512;
constexpr int NROWS = 1024;            // sensory 0..511, inter 512..1023
constexpr int NTGT  = NB * NH;         // 131072 targets

constexpr int THB   = 16;              // h columns register-blocked per thread
constexpr int NHT   = NH / THB;        // 32 h tiles
constexpr int CHUNK = 32;              // rows per LDS-staged chunk

// Odd poly for sigmoid(z), |z|<=7: sigma ~= fma(zc, P5(zc^2), 0.5), err ~3.5e-3.
__device__ __constant__ const float SC0 =  0.24781886f;
__device__ __constant__ const float SC1 = -0.01739900f;
__device__ __constant__ const float SC2 =  9.68558e-4f;
__device__ __constant__ const float SC3 = -3.09967e-5f;
__device__ __constant__ const float SC4 =  5.03772e-7f;
__device__ __constant__ const float SC5 = -3.21180e-9f;

__device__ __forceinline__ float clamp7(float z) {
#if __has_builtin(__builtin_amdgcn_fmed3f)
    return __builtin_amdgcn_fmed3f(z, -7.0f, 7.0f);   // v_med3_f32
#else
    return fminf(fmaxf(z, -7.0f), 7.0f);
#endif
}

// Block = (split s, h tile). Thread = batch b (0..255). Each thread owns
// 16 h columns in registers; block reduces rowsPerBlock = 1024>>sBits rows.
// Params are wave-uniform per (row, hh) -> scalar/K$ path, read once total.
__global__ __launch_bounds__(256, 4) void ltc_accum(
    const float* __restrict__ inputs,   // NB x 512
    const float* __restrict__ state,    // NB x 512
    const float* __restrict__ smu, const float* __restrict__ ssg,
    const float* __restrict__ sW,  const float* __restrict__ ser,
    const float* __restrict__ imu, const float* __restrict__ isg,
    const float* __restrict__ iW,  const float* __restrict__ ier,
    float2* __restrict__ part,
    int sBits)
{
    __shared__ float xs[CHUNK][NB + 1];   // [row][batch], +1 pad: both the
                                          // transposed fill and the b-indexed
                                          // read are bank-conflict-free
    const int bi    = blockIdx.x;
    const int S     = 1 << sBits;
    const int s     = bi & (S - 1);
    const int htile = bi >> sBits;              // 0..31
    const int h0    = htile * THB;
    const int rowsPerBlock = NROWS >> sBits;
    const int nchunk = rowsPerBlock / CHUNK;
    const int g0    = s * rowsPerBlock;
    const int b     = threadIdx.x;              // batch index

    float accN[THB], accD[THB];
#pragma unroll
    for (int hh = 0; hh < THB; ++hh) { accN[hh] = 0.f; accD[hh] = 0.f; }

    for (int c = 0; c < nchunk; ++c) {
        const int g    = g0 + c * CHUNK;        // global row base
        const bool sens = g < 512;
        const int  r0   = g & 511;

        const float* __restrict__ src = sens ? inputs : state;
        const float* __restrict__ Pmu = sens ? smu : imu;
        const float* __restrict__ Psg = sens ? ssg : isg;
        const float* __restrict__ PW  = sens ? sW  : iW;
        const float* __restrict__ Per = sens ? ser : ier;

        // Stage chunk: global read coalesced (consecutive tid -> consecutive
        // row elements), LDS write transposed, pad keeps banks distinct.
        if (c) __syncthreads();
#pragma unroll 4
        for (int k = 0; k < CHUNK; ++k) {
            const int lin = k * 256 + threadIdx.x;
            const int ii  = lin & (CHUNK - 1);
            const int bb  = lin >> 5;
            xs[ii][bb] = src[bb * 512 + r0 + ii];
        }
        __syncthreads();

        for (int ii = 0; ii < CHUNK; ++ii) {
            const float xv = xs[ii][b];              // lanes: consecutive b
            const int prow = (r0 + ii) * NH + h0;    // wave-uniform
#pragma unroll
            for (int hh = 0; hh < THB; ++hh) {
                const float a  = Psg[prow + hh];     // uniform -> s_load/K$
                const float cc = Pmu[prow + hh] * a;
                const float W  = PW [prow + hh];
                const float We = W * Per[prow + hh];
                const float z  = __builtin_fmaf(xv, a, -cc);
                const float zc = clamp7(z);
                const float sq = zc * zc;
                float pl = __builtin_fmaf(SC5, sq, SC4);
                pl = __builtin_fmaf(pl, sq, SC3);
                pl = __builtin_fmaf(pl, sq, SC2);
                pl = __builtin_fmaf(pl, sq, SC1);
                pl = __builtin_fmaf(pl, sq, SC0);
                const float sig = __builtin_fmaf(zc, pl, 0.5f);  // sigma(z)
                accD[hh] = __builtin_fmaf(W,  sig, accD[hh]);
                accN[hh] = __builtin_fmaf(We, sig, accN[hh]);
            }
        }
    }

    // Partial stores, h-major layout: part[s][h][b] -> lanes contiguous.
    float2* __restrict__ slice = part + (size_t)s * NTGT;
#pragma unroll
    for (int hh = 0; hh < THB; ++hh) {
        slice[(h0 + hh) * NB + b] = make_float2(accN[hh], accD[hh]);
    }
}

// Fused reduce + epilogue. Thread t: h = t>>8 (block-uniform), b = t&255.
// Partial reads coalesced; state/out accesses scattered but tiny (L2).
__global__ __launch_bounds__(256) void ltc_reduce_epilogue(
    const float* __restrict__ state,
    const float* __restrict__ vleak, const float* __restrict__ gleak,
    const float* __restrict__ cm,
    const float2* __restrict__ part, int S,
    float* __restrict__ out)
{
    const int t = blockIdx.x * 256 + threadIdx.x;  // h-major index
    const int h = t >> 8;
    const int b = t & (NB - 1);

    float wnum = 0.f, wden = 0.f;
    for (int s = 0; s < S; ++s) {
        const float2 p = part[(size_t)s * NTGT + t];   // coalesced
        wnum += p.x; wden += p.y;
    }

    const float st = state[b * NH + h];
    const float gl = gleak[h];
    const float vl = vleak[h];
    const float c  = cm[h];
    const float eps = 1e-8f;
    const float G = gl + wden;
    const float tau = c / (G + eps);
    const float numerator = c * st + gl * vl + wnum;
    const float denominator = c + G;
    const float v_inf = numerator / (denominator + eps);
    const float next = v_inf + (st - v_inf) * expf(-0.1f / (tau + eps));
    out[b * NH + h] = tanhf(next);
}

extern "C" void kernel_launch(void* const* d_in, const int* in_sizes, int n_in,
                              void* d_out, int out_size, void* d_ws, size_t ws_size,
                              hipStream_t stream) {
    const float* inputs = (const float*)d_in[0];
    const float* state  = (const float*)d_in[1];
    const float* smu    = (const float*)d_in[2];
    const float* ssg    = (const float*)d_in[3];
    const float* sW     = (const float*)d_in[4];
    const float* ser    = (const float*)d_in[5];
    const float* imu    = (const float*)d_in[6];
    const float* isg    = (const float*)d_in[7];
    const float* iW     = (const float*)d_in[8];
    const float* ier    = (const float*)d_in[9];
    const float* vleak  = (const float*)d_in[10];
    const float* gleak  = (const float*)d_in[11];
    const float* cm     = (const float*)d_in[12];

    // Split count: S=32 needs 33.5MB of ws (R9 showed ws = 256MiB); fallback S=8.
    const int sBits = (ws_size >= 32ull * NTGT * sizeof(float2)) ? 5 : 3;
    const int S     = 1 << sBits;

    float2* part = (float2*)d_ws;

    ltc_accum<<<dim3(NHT * S), dim3(256), 0, stream>>>(
        inputs, state, smu, ssg, sW, ser, imu, isg, iW, ier, part, sBits);
    ltc_reduce_epilogue<<<dim3(NTGT / 256), dim3(256), 0, stream>>>(
        state, vleak, gleak, cm, part, S, (float*)d_out);
}